// Round 2
// baseline (20545.760 us; speedup 1.0000x reference)
//
#include <hip/hip_runtime.h>
#include <hip/hip_bf16.h>
#include <hip/hip_cooperative_groups.h>
#include <math.h>

namespace cg = cooperative_groups;

#define BATCH 64
#define PIX   196
#define ENCD  2048
#define DECD  512
#define ATTD  512
#define EMBD  512
#define VOC   10000
#define LCAP  52
#define TSTEPS 51
#define XDIM  2560   // EMBD + ENCD
#define NBLK  512    // cooperative grid size (2 blocks/CU)

// ---------------- setup: stable descending argsort + int outputs ----------------
__global__ void k_setup(const int* caps, const int* lens,
                        int* order, int* declen,
                        float* caps_out, float* declen_out, float* order_out) {
    __shared__ int sl[64];
    __shared__ int so[64];
    int tid = threadIdx.x;
    sl[tid] = lens[tid];
    __syncthreads();
    int li = sl[tid];
    int pos = 0;
    for (int j = 0; j < 64; ++j) {
        int lj = sl[j];
        if (lj > li || (lj == li && j < tid)) pos++;
    }
    so[pos] = tid;
    __syncthreads();
    int ob = so[tid];
    order[tid] = ob;
    int dl = sl[ob] - 1;
    declen[tid] = dl;
    order_out[tid] = (float)ob;
    declen_out[tid] = (float)dl;
    for (int l = 0; l < LCAP; ++l)
        caps_out[tid * LCAP + l] = (float)caps[ob * LCAP + l];
}

// ---------------- mean over pixels (sorted order) ----------------
__global__ void k_mean(const float* enc, const int* order, float* meanv) {
    int b = blockIdx.x;
    int col = blockIdx.y * 256 + threadIdx.x;
    int ob = order[b];
    const float* base = enc + (size_t)ob * PIX * ENCD + col;
    float acc = 0.f;
    for (int p = 0; p < PIX; ++p) acc += base[(size_t)p * ENCD];
    meanv[b * ENCD + col] = acc * (1.0f / (float)PIX);
}

// ---------------- h0/c0 as 64x64-tiled GEMM: 16 blocks ----------------
__global__ __launch_bounds__(256) void k_h0c0(const float* meanv,
                                              const float* WH, const float* bH,
                                              const float* WC, const float* bC,
                                              float* h, float* c) {
    __shared__ float As[64 * 33];
    __shared__ float Bs[32 * 65];
    int nt = blockIdx.x, tid = threadIdx.x;
    const float* W; const float* bias; float* out; int j0;
    if (nt < 8) { W = WH; bias = bH; out = h; j0 = nt * 64; }
    else        { W = WC; bias = bC; out = c; j0 = (nt - 8) * 64; }
    float acc[4][4] = {};
    int tr = tid & 15, tc = tid >> 4;
    for (int k0 = 0; k0 < ENCD; k0 += 32) {
        for (int idx = tid; idx < 512; idx += 256) {
            int rl = idx >> 3, k4 = (idx & 7) << 2;
            float4 v = *(const float4*)(meanv + (size_t)rl * ENCD + k0 + k4);
            float* d = As + rl * 33 + k4;
            d[0] = v.x; d[1] = v.y; d[2] = v.z; d[3] = v.w;
        }
        for (int idx = tid; idx < 512; idx += 256) {
            int k = idx >> 4, j4 = (idx & 15) << 2;
            float4 v = *(const float4*)(W + (size_t)(k0 + k) * DECD + j0 + j4);
            float* d = Bs + k * 65 + j4;
            d[0] = v.x; d[1] = v.y; d[2] = v.z; d[3] = v.w;
        }
        __syncthreads();
        for (int kk = 0; kk < 32; ++kk) {
            float a[4], bb[4];
            for (int i = 0; i < 4; ++i) a[i] = As[(tr * 4 + i) * 33 + kk];
            for (int i = 0; i < 4; ++i) bb[i] = Bs[kk * 65 + tc * 4 + i];
            for (int i = 0; i < 4; ++i)
                for (int j2 = 0; j2 < 4; ++j2) acc[i][j2] += a[i] * bb[j2];
        }
        __syncthreads();
    }
    for (int i = 0; i < 4; ++i)
        for (int j2 = 0; j2 < 4; ++j2)
            out[(tr * 4 + i) * DECD + j0 + tc * 4 + j2] = acc[i][j2] + bias[j0 + tc * 4 + j2];
}

// ---------------- att1 = enc_sorted @ att_enc_W + b -> bf16 ----------------
__global__ __launch_bounds__(256) void k_att1(const float* enc, const int* order,
                                              const float* W, const float* bias,
                                              __hip_bfloat16* att1bf) {
    __shared__ float As[64][33];
    __shared__ float Bs[32][65];
    __shared__ int rbase[64];
    int rt = blockIdx.x, ct = blockIdx.y, tid = threadIdx.x;
    int a0 = ct * 64;
    if (tid < 64) {
        int r = rt * 64 + tid;
        int b = r / PIX, p = r % PIX;
        rbase[tid] = (order[b] * PIX + p) * ENCD;
    }
    __syncthreads();
    float acc[4][4] = {};
    int tr = tid % 16, tc = tid / 16;
    for (int k0 = 0; k0 < ENCD; k0 += 32) {
        for (int idx = tid; idx < 512; idx += 256) {
            int rl = idx / 8, k4 = (idx % 8) * 4;
            float4 v = *(const float4*)(enc + (size_t)rbase[rl] + k0 + k4);
            As[rl][k4] = v.x; As[rl][k4 + 1] = v.y; As[rl][k4 + 2] = v.z; As[rl][k4 + 3] = v.w;
        }
        for (int idx = tid; idx < 512; idx += 256) {
            int k = idx / 16, a4 = (idx % 16) * 4;
            float4 v = *(const float4*)(W + (size_t)(k0 + k) * ATTD + a0 + a4);
            Bs[k][a4] = v.x; Bs[k][a4 + 1] = v.y; Bs[k][a4 + 2] = v.z; Bs[k][a4 + 3] = v.w;
        }
        __syncthreads();
        for (int kk = 0; kk < 32; ++kk) {
            float a[4], bb[4];
            for (int i = 0; i < 4; ++i) a[i] = As[tr * 4 + i][kk];
            for (int i = 0; i < 4; ++i) bb[i] = Bs[kk][tc * 4 + i];
            for (int i = 0; i < 4; ++i)
                for (int j2 = 0; j2 < 4; ++j2) acc[i][j2] += a[i] * bb[j2];
        }
        __syncthreads();
    }
    int r0 = rt * 64;
    for (int i = 0; i < 4; ++i)
        for (int j2 = 0; j2 < 4; ++j2) {
            int r = r0 + tr * 4 + i, a = a0 + tc * 4 + j2;
            att1bf[(size_t)r * ATTD + a] = __float2bfloat16(acc[i][j2] + bias[a]);
        }
}

// ---------------- persistent cooperative kernel: the 51-step recurrence ----------------
struct CoopArgs {
    const float *enc, *embW, *Wad, *bad, *Wfb, *bfb, *wfull, *bfull;
    const float *Wih, *Whh, *bih, *bhh;
    const int *caps, *order, *declen;
    const __hip_bfloat16 *att1bf;
    float *att2, *gate, *x, *alpha, *partial, *h, *c, *hall, *alphas_out;
};

__global__ __launch_bounds__(256, 2) void k_coop(CoopArgs A) {
    cg::grid_group grid = cg::this_grid();
    __shared__ float smem[4416];
    const int tid = threadIdx.x;
    const int bid = blockIdx.x;
    const int nb  = gridDim.x;

    for (int t = 0; t < TSTEPS; ++t) {
        // ---------- Phase A: att2 (64 items) + gate (256 items) + emb copy (64 items) ----------
        for (int it = bid; it < 384; it += nb) {
            if (it < 320) {
                const float* W; int stride, j0, g; bool isG;
                if (it < 64) { int jc = it >> 3; g = it & 7; W = A.Wad; stride = ATTD; j0 = jc * 64; isG = false; }
                else { int q2 = it - 64; int jc = q2 >> 3; g = q2 & 7; W = A.Wfb; stride = ENCD; j0 = jc * 64; isG = true; }
                for (int i = tid; i < 1024; i += 256) {   // 8 rows x 512 via float4
                    int r = i >> 7, k4 = (i & 127) << 2;
                    float4 v = *(const float4*)(A.h + (size_t)(g * 8 + r) * DECD + k4);
                    float* d = smem + r * 512 + k4;
                    d[0] = v.x; d[1] = v.y; d[2] = v.z; d[3] = v.w;
                }
                __syncthreads();
                int c = tid & 63, q = tid >> 6;
                const float* hp0 = smem + q * 512;
                const float* hp1 = smem + (q + 4) * 512;
                const float* Wp = W + j0 + c;
                float acc0 = 0.f, acc1 = 0.f;
                for (int k = 0; k < 512; k += 4) {
                    float4 h0 = *(const float4*)(hp0 + k);
                    float4 h1 = *(const float4*)(hp1 + k);
                    float w0 = Wp[(size_t)k * stride];
                    float w1 = Wp[(size_t)(k + 1) * stride];
                    float w2 = Wp[(size_t)(k + 2) * stride];
                    float w3 = Wp[(size_t)(k + 3) * stride];
                    acc0 += w0 * h0.x + w1 * h0.y + w2 * h0.z + w3 * h0.w;
                    acc1 += w0 * h1.x + w1 * h1.y + w2 * h1.z + w3 * h1.w;
                }
                int b0 = g * 8 + q, b1 = b0 + 4;
                if (!isG) {
                    float bv = A.bad[j0 + c];
                    A.att2[b0 * ATTD + j0 + c] = acc0 + bv;
                    A.att2[b1 * ATTD + j0 + c] = acc1 + bv;
                } else {
                    float bv = A.bfb[j0 + c];
                    A.gate[b0 * ENCD + j0 + c] = 1.f / (1.f + expf(-(acc0 + bv)));
                    A.gate[b1 * ENCD + j0 + c] = 1.f / (1.f + expf(-(acc1 + bv)));
                }
                __syncthreads();
            } else {
                int b = it - 320;
                int tok = A.caps[A.order[b] * LCAP + t];
                const float4* ew = (const float4*)(A.embW + (size_t)tok * EMBD);
                float4* xd = (float4*)(A.x + (size_t)b * XDIM);
                for (int i = tid; i < 128; i += 256) xd[i] = ew[i];
            }
        }
        grid.sync();

        // ---------- Phase B: e scores + softmax -> alpha (64 items) ----------
        for (int it = bid; it < 64; it += nb) {
            int b = it;
            float* att2s = smem;          // 512
            float* es    = smem + 512;    // 256
            float* red   = smem + 768;    // 256
            for (int i = tid; i < 512; i += 256) att2s[i] = A.att2[b * ATTD + i];
            __syncthreads();
            int wv = tid >> 6, lane = tid & 63;
            for (int p = wv; p < PIX; p += 4) {
                const __hip_bfloat16* a1 = A.att1bf + ((size_t)b * PIX + p) * ATTD;
                float acc = 0.f;
                for (int j = 0; j < 8; ++j) {
                    int a = j * 64 + lane;
                    float v = __bfloat162float(a1[a]) + att2s[a];
                    v = fmaxf(v, 0.f);
                    acc += v * A.wfull[a];
                }
                for (int off = 32; off; off >>= 1) acc += __shfl_down(acc, off);
                if (lane == 0) es[p] = acc;
            }
            __syncthreads();
            float ev = (tid < PIX) ? es[tid] + A.bfull[0] : -1e30f;
            red[tid] = ev; __syncthreads();
            for (int s = 128; s; s >>= 1) { if (tid < s) red[tid] = fmaxf(red[tid], red[tid + s]); __syncthreads(); }
            float m = red[0]; __syncthreads();
            float pv = (tid < PIX) ? expf(ev - m) : 0.f;
            red[tid] = pv; __syncthreads();
            for (int s = 128; s; s >>= 1) { if (tid < s) red[tid] += red[tid + s]; __syncthreads(); }
            float inv = 1.f / red[0];
            float al = pv * inv;
            if (tid < PIX) {
                A.alpha[b * PIX + tid] = al;
                bool mask = t < A.declen[b];
                A.alphas_out[((size_t)b * TSTEPS + t) * PIX + tid] = mask ? al : 0.f;
            }
            __syncthreads();
        }
        grid.sync();

        // ---------- Phase C: awe + x[:,512:] (512 items: b x 8 col-chunks) ----------
        for (int it = bid; it < 512; it += nb) {
            int b = it >> 3, ch = it & 7;
            for (int i = tid; i < PIX; i += 256) smem[i] = A.alpha[b * PIX + i];
            __syncthreads();
            int col = ch * 256 + tid;
            const float* ep = A.enc + (size_t)A.order[b] * PIX * ENCD + col;
            float acc = 0.f;
            for (int p = 0; p < PIX; ++p) acc += smem[p] * ep[(size_t)p * ENCD];
            A.x[(size_t)b * XDIM + EMBD + col] = A.gate[b * ENCD + col] * acc;
            __syncthreads();
        }
        grid.sync();

        // ---------- Phase D: gates partial GEMM (384 items: 32 j-tiles x 12 K-chunks) ----------
        for (int it = bid; it < 384; it += nb) {
            int jt = it & 31, kc = it >> 5;
            int j0 = jt * 64, kg = kc * 256;
            const float* Ap; int sA; const float* Bp; int sB;
            if (kc < 10) { Ap = A.x + kg; sA = XDIM; Bp = A.Wih + kg; sB = XDIM; }
            else         { Ap = A.h + (kg - XDIM); sA = DECD; Bp = A.Whh + (kg - XDIM); sB = DECD; }
            float acc[4][4] = {};
            int tr = tid & 15, tc = tid >> 4;
            float* As = smem;            // 64*33
            float* Bs = smem + 2112;     // 32*65
            for (int k0 = 0; k0 < 256; k0 += 32) {
                for (int idx = tid; idx < 512; idx += 256) {
                    int rl = idx >> 3, k4 = (idx & 7) << 2;
                    float4 v = *(const float4*)(Ap + (size_t)rl * sA + k0 + k4);
                    float* d = As + rl * 33 + k4;
                    d[0] = v.x; d[1] = v.y; d[2] = v.z; d[3] = v.w;
                }
                for (int idx = tid; idx < 512; idx += 256) {
                    int jl = idx >> 3, k4 = (idx & 7) << 2;
                    float4 v = *(const float4*)(Bp + (size_t)(j0 + jl) * sB + k0 + k4);
                    Bs[(k4 + 0) * 65 + jl] = v.x; Bs[(k4 + 1) * 65 + jl] = v.y;
                    Bs[(k4 + 2) * 65 + jl] = v.z; Bs[(k4 + 3) * 65 + jl] = v.w;
                }
                __syncthreads();
                for (int kk = 0; kk < 32; ++kk) {
                    float a[4], bb[4];
                    for (int i2 = 0; i2 < 4; ++i2) a[i2] = As[(tr * 4 + i2) * 33 + kk];
                    for (int i2 = 0; i2 < 4; ++i2) bb[i2] = Bs[kk * 65 + tc * 4 + i2];
                    for (int i2 = 0; i2 < 4; ++i2)
                        for (int j2 = 0; j2 < 4; ++j2) acc[i2][j2] += a[i2] * bb[j2];
                }
                __syncthreads();
            }
            float* out = A.partial + (size_t)kc * (64 * 2048);
            for (int i2 = 0; i2 < 4; ++i2)
                for (int j2 = 0; j2 < 4; ++j2)
                    out[(tr * 4 + i2) * 2048 + j0 + tc * 4 + j2] = acc[i2][j2];
        }
        grid.sync();

        // ---------- Phase E: LSTM pointwise update (64 items) ----------
        for (int it = bid; it < 64; it += nb) {
            int b = it;
            bool mask = t < A.declen[b];
            for (int d = tid; d < 512; d += 256) {
                float gg[4];
                for (int q = 0; q < 4; ++q) {
                    int j = q * 512 + d;
                    float acc = A.bih[j] + A.bhh[j];
                    for (int kc = 0; kc < 12; ++kc)
                        acc += A.partial[(size_t)kc * 131072 + b * 2048 + j];
                    gg[q] = acc;
                }
                float si = 1.f / (1.f + expf(-gg[0]));
                float sf = 1.f / (1.f + expf(-gg[1]));
                float gt = tanhf(gg[2]);
                float so = 1.f / (1.f + expf(-gg[3]));
                float c_old = A.c[b * DECD + d], h_old = A.h[b * DECD + d];
                float c_new = sf * c_old + si * gt;
                float h_new = so * tanhf(c_new);
                A.h[b * DECD + d] = mask ? h_new : h_old;
                A.c[b * DECD + d] = mask ? c_new : c_old;
                A.hall[((size_t)t * 64 + b) * DECD + d] = h_new;
            }
        }
        grid.sync();
    }
}

// ---------------- batched fc: preds[b,t,:] = mask ? hall[t,b,:]@fc_W + fc_b : 0 ----------------
__global__ __launch_bounds__(256) void k_fc(const float* hall, const float* W,
                                            const float* bias, const int* declen,
                                            float* preds) {
    __shared__ float As[64][33];
    __shared__ float Bs[32][65];
    int vt = blockIdx.x, tt = blockIdx.y, tid = threadIdx.x;
    int v0 = vt * 64;
    const float* A = hall + (size_t)tt * 64 * DECD;
    float acc[4][4] = {};
    int tr = tid % 16, tc = tid / 16;
    for (int k0 = 0; k0 < DECD; k0 += 32) {
        for (int idx = tid; idx < 512; idx += 256) {
            int rl = idx / 8, k4 = (idx % 8) * 4;
            float4 v = *(const float4*)(A + (size_t)rl * DECD + k0 + k4);
            As[rl][k4] = v.x; As[rl][k4 + 1] = v.y; As[rl][k4 + 2] = v.z; As[rl][k4 + 3] = v.w;
        }
        for (int idx = tid; idx < 512; idx += 256) {
            int k = idx / 16, v4 = (idx % 16) * 4;
            float4 v = make_float4(0.f, 0.f, 0.f, 0.f);
            if (v0 + v4 + 3 < VOC) v = *(const float4*)(W + (size_t)(k0 + k) * VOC + v0 + v4);
            Bs[k][v4] = v.x; Bs[k][v4 + 1] = v.y; Bs[k][v4 + 2] = v.z; Bs[k][v4 + 3] = v.w;
        }
        __syncthreads();
        for (int kk = 0; kk < 32; ++kk) {
            float a[4], bb[4];
            for (int i = 0; i < 4; ++i) a[i] = As[tr * 4 + i][kk];
            for (int i = 0; i < 4; ++i) bb[i] = Bs[kk][tc * 4 + i];
            for (int i = 0; i < 4; ++i)
                for (int j2 = 0; j2 < 4; ++j2) acc[i][j2] += a[i] * bb[j2];
        }
        __syncthreads();
    }
    for (int i = 0; i < 4; ++i) {
        int b = tr * 4 + i;
        bool mask = tt < declen[b];
        for (int j2 = 0; j2 < 4; ++j2) {
            int v = v0 + tc * 4 + j2;
            if (v < VOC)
                preds[((size_t)b * TSTEPS + tt) * VOC + v] = mask ? (acc[i][j2] + bias[v]) : 0.f;
        }
    }
}

extern "C" void kernel_launch(void* const* d_in, const int* in_sizes, int n_in,
                              void* d_out, int out_size, void* d_ws, size_t ws_size,
                              hipStream_t stream) {
    const float* enc      = (const float*)d_in[0];
    const int*   caps     = (const int*)d_in[1];
    const int*   lens     = (const int*)d_in[2];
    const float* embW     = (const float*)d_in[3];
    const float* att_enc_W = (const float*)d_in[4];
    const float* att_enc_b = (const float*)d_in[5];
    const float* att_dec_W = (const float*)d_in[6];
    const float* att_dec_b = (const float*)d_in[7];
    const float* att_full_w = (const float*)d_in[8];
    const float* att_full_b = (const float*)d_in[9];
    const float* lstm_Wih = (const float*)d_in[10];
    const float* lstm_Whh = (const float*)d_in[11];
    const float* lstm_bih = (const float*)d_in[12];
    const float* lstm_bhh = (const float*)d_in[13];
    const float* initH_W  = (const float*)d_in[14];
    const float* initH_b  = (const float*)d_in[15];
    const float* initC_W  = (const float*)d_in[16];
    const float* initC_b  = (const float*)d_in[17];
    const float* fbeta_W  = (const float*)d_in[18];
    const float* fbeta_b  = (const float*)d_in[19];
    const float* fc_W     = (const float*)d_in[20];
    const float* fc_b     = (const float*)d_in[21];

    // outputs (flat f32): preds | caps | dec_len | alphas | order
    float* o = (float*)d_out;
    float* preds_out  = o;
    float* caps_out   = o + (size_t)BATCH * TSTEPS * VOC;
    float* declen_out = caps_out + (size_t)BATCH * LCAP;
    float* order_out  = declen_out + BATCH;
    float* alphas_out = order_out + BATCH;

    // workspace layout
    char* wsb = (char*)d_ws;
    int* i_order  = (int*)wsb;
    int* i_declen = i_order + 64;
    float* f = (float*)(wsb + 512);
    float* f_mean  = f;  f += (size_t)BATCH * ENCD;
    float* f_h     = f;  f += (size_t)BATCH * DECD;
    float* f_c     = f;  f += (size_t)BATCH * DECD;
    float* f_att2  = f;  f += (size_t)BATCH * ATTD;
    float* f_gate  = f;  f += (size_t)BATCH * ENCD;
    float* f_x     = f;  f += (size_t)BATCH * XDIM;
    float* f_alpha = f;  f += (size_t)BATCH * PIX;
    f = (float*)(((uintptr_t)f + 255) & ~(uintptr_t)255);
    __hip_bfloat16* bf_att1 = (__hip_bfloat16*)f;
    f = (float*)(((uintptr_t)(bf_att1 + (size_t)BATCH * PIX * ATTD) + 255) & ~(uintptr_t)255);
    float* f_part  = f;  f += (size_t)12 * BATCH * 2048;
    float* f_hall  = f;  f += (size_t)TSTEPS * BATCH * DECD;

    k_setup<<<1, 64, 0, stream>>>(caps, lens, i_order, i_declen,
                                  caps_out, declen_out, order_out);
    k_mean<<<dim3(BATCH, ENCD / 256), 256, 0, stream>>>(enc, i_order, f_mean);
    k_h0c0<<<16, 256, 0, stream>>>(f_mean, initH_W, initH_b, initC_W, initC_b,
                                   f_h, f_c);
    k_att1<<<dim3(196, 8), 256, 0, stream>>>(enc, i_order, att_enc_W, att_enc_b,
                                             bf_att1);

    CoopArgs ca;
    ca.enc = enc; ca.embW = embW;
    ca.Wad = att_dec_W; ca.bad = att_dec_b;
    ca.Wfb = fbeta_W;   ca.bfb = fbeta_b;
    ca.wfull = att_full_w; ca.bfull = att_full_b;
    ca.Wih = lstm_Wih; ca.Whh = lstm_Whh; ca.bih = lstm_bih; ca.bhh = lstm_bhh;
    ca.caps = caps; ca.order = i_order; ca.declen = i_declen;
    ca.att1bf = bf_att1;
    ca.att2 = f_att2; ca.gate = f_gate; ca.x = f_x; ca.alpha = f_alpha;
    ca.partial = f_part; ca.h = f_h; ca.c = f_c; ca.hall = f_hall;
    ca.alphas_out = alphas_out;

    void* kargs[] = { &ca };
    hipLaunchCooperativeKernel((void*)k_coop, dim3(NBLK), dim3(256), kargs, 0, stream);

    k_fc<<<dim3((VOC + 63) / 64, TSTEPS), 256, 0, stream>>>(f_hall, fc_W, fc_b,
                                                            i_declen, preds_out);
}

// Round 3
// 7203.649 us; speedup vs baseline: 2.8521x; 2.8521x over previous
//
#include <hip/hip_runtime.h>
#include <math.h>

#define BATCH 64
#define PIX   196
#define ENCD  2048
#define DECD  512
#define ATTD  512
#define EMBD  512
#define VOC   10000
#define LCAP  52
#define TSTEPS 51
#define XHDIM 3072   // emb(512) | gated awe(2048) | h(512)

__device__ __forceinline__ float bf2f(unsigned short u) {
    union { unsigned int i; float f; } x; x.i = ((unsigned int)u) << 16; return x.f;
}
__device__ __forceinline__ unsigned short f2bf(float f) {
    union { float f; unsigned int i; } x; x.f = f;
    unsigned int r = x.i + 0x7fffu + ((x.i >> 16) & 1u);
    return (unsigned short)(r >> 16);
}

// ---------------- setup: stable descending argsort + int outputs ----------------
__global__ void k_setup(const int* caps, const int* lens,
                        int* order, int* declen,
                        float* caps_out, float* declen_out, float* order_out) {
    __shared__ int sl[64];
    __shared__ int so[64];
    int tid = threadIdx.x;
    sl[tid] = lens[tid];
    __syncthreads();
    int li = sl[tid];
    int pos = 0;
    for (int j = 0; j < 64; ++j) {
        int lj = sl[j];
        if (lj > li || (lj == li && j < tid)) pos++;
    }
    so[pos] = tid;
    __syncthreads();
    int ob = so[tid];
    order[tid] = ob;
    int dl = sl[ob] - 1;
    declen[tid] = dl;
    order_out[tid] = (float)ob;
    declen_out[tid] = (float)dl;
    for (int l = 0; l < LCAP; ++l)
        caps_out[tid * LCAP + l] = (float)caps[ob * LCAP + l];
}

// ---------------- one-time converts ----------------
__global__ void k_cvt(const float* s, unsigned short* d, int n) {
    int i = (blockIdx.x * 256 + threadIdx.x) * 4;
    if (i + 3 < n) {
        float4 v = *(const float4*)(s + i);
        ushort4 o;
        o.x = f2bf(v.x); o.y = f2bf(v.y); o.z = f2bf(v.z); o.w = f2bf(v.w);
        *(ushort4*)(d + i) = o;
    }
}

// Wcomb[j][k] = k<2560 ? Wih[j][k] : Whh[j][k-2560]   (bf16, row-major 2048x3072)
__global__ void k_cvt_comb(const float* Wih, const float* Whh, unsigned short* W) {
    int j = blockIdx.x, tid = threadIdx.x;
    for (int k = tid * 4; k < XHDIM; k += 1024) {
        const float* src = (k < 2560) ? (Wih + (size_t)j * 2560 + k)
                                      : (Whh + (size_t)j * 512 + (k - 2560));
        float4 v = *(const float4*)src;
        ushort4 o;
        o.x = f2bf(v.x); o.y = f2bf(v.y); o.z = f2bf(v.z); o.w = f2bf(v.w);
        *(ushort4*)(W + (size_t)j * XHDIM + k) = o;
    }
}

// enc_bf[b][p][c] = bf16(enc[order[b]][p][c])  (sorted order baked in)
__global__ void k_cvt_enc(const float* enc, const int* order, unsigned short* enc_bf) {
    int b = blockIdx.x, p = blockIdx.y, tid = threadIdx.x;
    const float* src = enc + ((size_t)order[b] * PIX + p) * ENCD + tid * 8;
    float4 v0 = *(const float4*)src;
    float4 v1 = *(const float4*)(src + 4);
    unsigned short o[8];
    o[0] = f2bf(v0.x); o[1] = f2bf(v0.y); o[2] = f2bf(v0.z); o[3] = f2bf(v0.w);
    o[4] = f2bf(v1.x); o[5] = f2bf(v1.y); o[6] = f2bf(v1.z); o[7] = f2bf(v1.w);
    *(uint4*)(enc_bf + ((size_t)b * PIX + p) * ENCD + tid * 8) = *(uint4*)o;
}

// ---------------- mean over pixels (sorted order) ----------------
__global__ void k_mean(const float* enc, const int* order, float* meanv) {
    int b = blockIdx.x;
    int col = blockIdx.y * 256 + threadIdx.x;
    int ob = order[b];
    const float* base = enc + (size_t)ob * PIX * ENCD + col;
    float acc = 0.f;
    for (int p = 0; p < PIX; ++p) acc += base[(size_t)p * ENCD];
    meanv[b * ENCD + col] = acc * (1.0f / (float)PIX);
}

// ---------------- h0/c0 tiled GEMM; h path also seeds xh h-slot ----------------
__global__ __launch_bounds__(256) void k_h0c0(const float* meanv,
                                              const float* WH, const float* bH,
                                              const float* WC, const float* bC,
                                              float* h, float* c, unsigned short* xh) {
    __shared__ float As[64 * 33];
    __shared__ float Bs[32 * 65];
    int nt = blockIdx.x, tid = threadIdx.x;
    const float* W; const float* bias; float* out; int j0; bool isH;
    if (nt < 8) { W = WH; bias = bH; out = h; j0 = nt * 64; isH = true; }
    else        { W = WC; bias = bC; out = c; j0 = (nt - 8) * 64; isH = false; }
    float acc[4][4] = {};
    int tr = tid & 15, tc = tid >> 4;
    for (int k0 = 0; k0 < ENCD; k0 += 32) {
        for (int idx = tid; idx < 512; idx += 256) {
            int rl = idx >> 3, k4 = (idx & 7) << 2;
            float4 v = *(const float4*)(meanv + (size_t)rl * ENCD + k0 + k4);
            float* d = As + rl * 33 + k4;
            d[0] = v.x; d[1] = v.y; d[2] = v.z; d[3] = v.w;
        }
        for (int idx = tid; idx < 512; idx += 256) {
            int k = idx >> 4, j4 = (idx & 15) << 2;
            float4 v = *(const float4*)(W + (size_t)(k0 + k) * DECD + j0 + j4);
            float* d = Bs + k * 65 + j4;
            d[0] = v.x; d[1] = v.y; d[2] = v.z; d[3] = v.w;
        }
        __syncthreads();
        for (int kk = 0; kk < 32; ++kk) {
            float a[4], bb[4];
            for (int i = 0; i < 4; ++i) a[i] = As[(tr * 4 + i) * 33 + kk];
            for (int i = 0; i < 4; ++i) bb[i] = Bs[kk * 65 + tc * 4 + i];
            for (int i = 0; i < 4; ++i)
                for (int j2 = 0; j2 < 4; ++j2) acc[i][j2] += a[i] * bb[j2];
        }
        __syncthreads();
    }
    for (int i = 0; i < 4; ++i)
        for (int j2 = 0; j2 < 4; ++j2) {
            int r = tr * 4 + i, j = j0 + tc * 4 + j2;
            float v = acc[i][j2] + bias[j];
            out[r * DECD + j] = v;
            if (isH) xh[(size_t)r * XHDIM + 2560 + j] = f2bf(v);
        }
}

// ---------------- att1 = enc_sorted @ att_enc_W + b -> bf16 ----------------
__global__ __launch_bounds__(256) void k_att1(const float* enc, const int* order,
                                              const float* W, const float* bias,
                                              unsigned short* att1bf) {
    __shared__ float As[64][33];
    __shared__ float Bs[32][65];
    __shared__ int rbase[64];
    int rt = blockIdx.x, ct = blockIdx.y, tid = threadIdx.x;
    int a0 = ct * 64;
    if (tid < 64) {
        int r = rt * 64 + tid;
        int b = r / PIX, p = r % PIX;
        rbase[tid] = (order[b] * PIX + p) * ENCD;
    }
    __syncthreads();
    float acc[4][4] = {};
    int tr = tid % 16, tc = tid / 16;
    for (int k0 = 0; k0 < ENCD; k0 += 32) {
        for (int idx = tid; idx < 512; idx += 256) {
            int rl = idx / 8, k4 = (idx % 8) * 4;
            float4 v = *(const float4*)(enc + (size_t)rbase[rl] + k0 + k4);
            As[rl][k4] = v.x; As[rl][k4 + 1] = v.y; As[rl][k4 + 2] = v.z; As[rl][k4 + 3] = v.w;
        }
        for (int idx = tid; idx < 512; idx += 256) {
            int k = idx / 16, a4 = (idx % 16) * 4;
            float4 v = *(const float4*)(W + (size_t)(k0 + k) * ATTD + a0 + a4);
            Bs[k][a4] = v.x; Bs[k][a4 + 1] = v.y; Bs[k][a4 + 2] = v.z; Bs[k][a4 + 3] = v.w;
        }
        __syncthreads();
        for (int kk = 0; kk < 32; ++kk) {
            float a[4], bb[4];
            for (int i = 0; i < 4; ++i) a[i] = As[tr * 4 + i][kk];
            for (int i = 0; i < 4; ++i) bb[i] = Bs[kk][tc * 4 + i];
            for (int i = 0; i < 4; ++i)
                for (int j2 = 0; j2 < 4; ++j2) acc[i][j2] += a[i] * bb[j2];
        }
        __syncthreads();
    }
    int r0 = rt * 64;
    for (int i = 0; i < 4; ++i)
        for (int j2 = 0; j2 < 4; ++j2) {
            int r = r0 + tr * 4 + i, a = a0 + tc * 4 + j2;
            att1bf[(size_t)r * ATTD + a] = f2bf(acc[i][j2] + bias[a]);
        }
}

// ---------------- per step: att2 / gate GEMV (bf16 W) + emb -> xh ----------------
__global__ void k_att2gate(const float* h, const unsigned short* Wad, const float* bad,
                           const unsigned short* Wfb, const float* bfb,
                           const float* embW, const int* caps, const int* order,
                           float* att2, float* gate, unsigned short* xh, int t) {
    __shared__ float Hs[8][64];
    int jt = blockIdx.x, bg = blockIdx.y, tid = threadIdx.x;
    int j = jt * 256 + tid;   // j<512 -> att2 col j ; else gate col j-512
    float acc[8] = {};
    for (int k0 = 0; k0 < DECD; k0 += 64) {
        for (int idx = tid; idx < 512; idx += 256) {
            int bb = idx / 64, kk = idx % 64;
            Hs[bb][kk] = h[(bg * 8 + bb) * DECD + k0 + kk];
        }
        __syncthreads();
        if (j < 512) {
            for (int kk = 0; kk < 64; ++kk) {
                float w = bf2f(Wad[(size_t)(k0 + kk) * ATTD + j]);
                for (int bb = 0; bb < 8; ++bb) acc[bb] += w * Hs[bb][kk];
            }
        } else {
            int jj = j - 512;
            for (int kk = 0; kk < 64; ++kk) {
                float w = bf2f(Wfb[(size_t)(k0 + kk) * ENCD + jj]);
                for (int bb = 0; bb < 8; ++bb) acc[bb] += w * Hs[bb][kk];
            }
        }
        __syncthreads();
    }
    if (j < 512) {
        float bv = bad[j];
        for (int bb = 0; bb < 8; ++bb)
            att2[(bg * 8 + bb) * ATTD + j] = acc[bb] + bv;
    } else {
        int jj = j - 512;
        float bv = bfb[jj];
        for (int bb = 0; bb < 8; ++bb)
            gate[(bg * 8 + bb) * ENCD + jj] = 1.f / (1.f + expf(-(acc[bb] + bv)));
    }
    if (jt == 0) {
        for (int bb = 0; bb < 8; ++bb) {
            int b = bg * 8 + bb;
            int tok = caps[order[b] * LCAP + t];
            for (int idx = tid; idx < EMBD; idx += 256)
                xh[(size_t)b * XHDIM + idx] = f2bf(embW[(size_t)tok * EMBD + idx]);
        }
    }
}

// ---------------- e[b,p] = relu(att1+att2).wfull + bfull  (vectored bf16) ----------------
__global__ void k_e(const unsigned short* att1bf, const float* att2,
                    const float* wfull, const float* bfull, float* e) {
    __shared__ float a2s[512];
    __shared__ float wfs[512];
    int b = blockIdx.x, tid = threadIdx.x;
    a2s[tid] = att2[b * ATTD + tid];
    a2s[tid + 256] = att2[b * ATTD + tid + 256];
    wfs[tid] = wfull[tid];
    wfs[tid + 256] = wfull[tid + 256];
    __syncthreads();
    int p = blockIdx.y * 4 + (tid >> 6);
    int lane = tid & 63;
    uint4 v = *(const uint4*)(att1bf + ((size_t)b * PIX + p) * ATTD + lane * 8);
    const unsigned short* us = (const unsigned short*)&v;
    float acc = 0.f;
    for (int jj = 0; jj < 8; ++jj) {
        int a = lane * 8 + jj;
        float x = bf2f(us[jj]) + a2s[a];
        x = fmaxf(x, 0.f);
        acc += x * wfs[a];
    }
    for (int off = 32; off; off >>= 1) acc += __shfl_down(acc, off);
    if (lane == 0) e[b * PIX + p] = acc + bfull[0];
}

// ---------------- softmax + awe + gated x -> xh (+ alphas out) ----------------
__global__ void k_awe(const float* e, const unsigned short* enc_bf,
                      const float* gate, const int* declen,
                      unsigned short* xh, float* alphas_out, int t) {
    __shared__ float sal[256];
    __shared__ float sred[256];
    __shared__ float sacc[2048];   // 8 p-groups x 256 cols
    int b = blockIdx.x, ch = blockIdx.y, tid = threadIdx.x;
    float ev = (tid < PIX) ? e[b * PIX + tid] : -1e30f;
    sred[tid] = ev; __syncthreads();
    for (int s = 128; s; s >>= 1) { if (tid < s) sred[tid] = fmaxf(sred[tid], sred[tid + s]); __syncthreads(); }
    float m = sred[0]; __syncthreads();
    float pv = (tid < PIX) ? expf(ev - m) : 0.f;
    sred[tid] = pv; __syncthreads();
    for (int s = 128; s; s >>= 1) { if (tid < s) sred[tid] += sred[tid + s]; __syncthreads(); }
    float inv = 1.f / sred[0];
    float al = pv * inv;
    sal[tid] = al;
    if (ch == 0 && tid < PIX) {
        bool mask = t < declen[b];
        alphas_out[((size_t)b * TSTEPS + t) * PIX + tid] = mask ? al : 0.f;
    }
    __syncthreads();
    int g = tid & 31, pp = tid >> 5;
    float acc[8] = {};
    const unsigned short* base = enc_bf + (size_t)b * PIX * ENCD + ch * 256 + g * 8;
    for (int p = pp; p < PIX; p += 8) {
        uint4 v = *(const uint4*)(base + (size_t)p * ENCD);
        const unsigned short* us = (const unsigned short*)&v;
        float a = sal[p];
        for (int jj = 0; jj < 8; ++jj) acc[jj] += a * bf2f(us[jj]);
    }
    for (int jj = 0; jj < 8; ++jj) sacc[pp * 256 + g * 8 + jj] = acc[jj];
    __syncthreads();
    float s = 0.f;
    for (int q = 0; q < 8; ++q) s += sacc[q * 256 + tid];
    int col = ch * 256 + tid;
    xh[(size_t)b * XHDIM + EMBD + col] = f2bf(gate[b * ENCD + col] * s);
}

// ---------------- gates partial GEMM (bf16): partial[kc] = xh_chunk @ Wcomb_chunk^T ----------------
__global__ __launch_bounds__(256) void k_gates(const unsigned short* xh,
                                               const unsigned short* W,
                                               float* partial) {
    __shared__ float As[64 * 33];
    __shared__ float Bs[32 * 65];
    int jt = blockIdx.x, kc = blockIdx.y, tid = threadIdx.x;
    int j0 = jt * 64, kg = kc * 512;
    float acc[4][4] = {};
    int tr = tid & 15, tc = tid >> 4;
    for (int k0 = 0; k0 < 512; k0 += 32) {
        int kb = kg + k0;
        {
            int rl = tid >> 2, k8 = (tid & 3) * 8;
            uint4 v = *(const uint4*)(xh + (size_t)rl * XHDIM + kb + k8);
            const unsigned short* us = (const unsigned short*)&v;
            float* d = As + rl * 33 + k8;
            for (int jj = 0; jj < 8; ++jj) d[jj] = bf2f(us[jj]);
        }
        {
            int jl = tid >> 2, k8 = (tid & 3) * 8;
            uint4 v = *(const uint4*)(W + (size_t)(j0 + jl) * XHDIM + kb + k8);
            const unsigned short* us = (const unsigned short*)&v;
            for (int jj = 0; jj < 8; ++jj) Bs[(k8 + jj) * 65 + jl] = bf2f(us[jj]);
        }
        __syncthreads();
        for (int kk = 0; kk < 32; ++kk) {
            float a[4], bb[4];
            for (int i2 = 0; i2 < 4; ++i2) a[i2] = As[(tr * 4 + i2) * 33 + kk];
            for (int i2 = 0; i2 < 4; ++i2) bb[i2] = Bs[kk * 65 + tc * 4 + i2];
            for (int i2 = 0; i2 < 4; ++i2)
                for (int j2 = 0; j2 < 4; ++j2) acc[i2][j2] += a[i2] * bb[j2];
        }
        __syncthreads();
    }
    float* out = partial + (size_t)kc * (64 * 2048);
    for (int i2 = 0; i2 < 4; ++i2)
        for (int j2 = 0; j2 < 4; ++j2)
            out[(tr * 4 + i2) * 2048 + j0 + tc * 4 + j2] = acc[i2][j2];
}

// ---------------- LSTM pointwise update ----------------
__global__ void k_update(const float* partial, const float* bih, const float* bhh,
                         const int* declen, float* h, float* c, float* hall,
                         unsigned short* xh, int t) {
    int b = blockIdx.x, d = threadIdx.x;
    float g[4];
    for (int q = 0; q < 4; ++q) {
        int j = q * 512 + d;
        float acc = bih[j] + bhh[j];
        for (int kc = 0; kc < 6; ++kc) acc += partial[(size_t)kc * 131072 + b * 2048 + j];
        g[q] = acc;
    }
    float si = 1.f / (1.f + expf(-g[0]));
    float sf = 1.f / (1.f + expf(-g[1]));
    float gg = tanhf(g[2]);
    float so = 1.f / (1.f + expf(-g[3]));
    float c_old = c[b * DECD + d], h_old = h[b * DECD + d];
    float c_new = sf * c_old + si * gg;
    float h_new = so * tanhf(c_new);
    bool mask = t < declen[b];
    float h_keep = mask ? h_new : h_old;
    h[b * DECD + d] = h_keep;
    c[b * DECD + d] = mask ? c_new : c_old;
    xh[(size_t)b * XHDIM + 2560 + d] = f2bf(h_keep);
    hall[((size_t)t * 64 + b) * DECD + d] = h_new;
}

// ---------------- batched fc (bf16 W): preds = mask ? hall@fc_W + fc_b : 0 ----------------
__global__ __launch_bounds__(256) void k_fc(const float* hall, const unsigned short* Wbf,
                                            const float* bias, const int* declen,
                                            float* preds) {
    __shared__ float As[64][33];
    __shared__ float Bs[32][65];
    int vt = blockIdx.x, tt = blockIdx.y, tid = threadIdx.x;
    int v0 = vt * 64;
    const float* A = hall + (size_t)tt * 64 * DECD;
    float acc[4][4] = {};
    int tr = tid % 16, tc = tid / 16;
    for (int k0 = 0; k0 < DECD; k0 += 32) {
        for (int idx = tid; idx < 512; idx += 256) {
            int rl = idx / 8, k4 = (idx % 8) * 4;
            float4 v = *(const float4*)(A + (size_t)rl * DECD + k0 + k4);
            As[rl][k4] = v.x; As[rl][k4 + 1] = v.y; As[rl][k4 + 2] = v.z; As[rl][k4 + 3] = v.w;
        }
        for (int idx = tid; idx < 512; idx += 256) {
            int k = idx / 16, v4 = (idx % 16) * 4;
            float vals[4] = {0.f, 0.f, 0.f, 0.f};
            if (v0 + v4 + 3 < VOC) {
                ushort4 u = *(const ushort4*)(Wbf + (size_t)(k0 + k) * VOC + v0 + v4);
                vals[0] = bf2f(u.x); vals[1] = bf2f(u.y); vals[2] = bf2f(u.z); vals[3] = bf2f(u.w);
            }
            Bs[k][v4] = vals[0]; Bs[k][v4 + 1] = vals[1]; Bs[k][v4 + 2] = vals[2]; Bs[k][v4 + 3] = vals[3];
        }
        __syncthreads();
        for (int kk = 0; kk < 32; ++kk) {
            float a[4], bb[4];
            for (int i = 0; i < 4; ++i) a[i] = As[tr * 4 + i][kk];
            for (int i = 0; i < 4; ++i) bb[i] = Bs[kk][tc * 4 + i];
            for (int i = 0; i < 4; ++i)
                for (int j2 = 0; j2 < 4; ++j2) acc[i][j2] += a[i] * bb[j2];
        }
        __syncthreads();
    }
    for (int i = 0; i < 4; ++i) {
        int b = tr * 4 + i;
        bool mask = tt < declen[b];
        for (int j2 = 0; j2 < 4; ++j2) {
            int v = v0 + tc * 4 + j2;
            if (v < VOC)
                preds[((size_t)b * TSTEPS + tt) * VOC + v] = mask ? (acc[i][j2] + bias[v]) : 0.f;
        }
    }
}

extern "C" void kernel_launch(void* const* d_in, const int* in_sizes, int n_in,
                              void* d_out, int out_size, void* d_ws, size_t ws_size,
                              hipStream_t stream) {
    const float* enc      = (const float*)d_in[0];
    const int*   caps     = (const int*)d_in[1];
    const int*   lens     = (const int*)d_in[2];
    const float* embW     = (const float*)d_in[3];
    const float* att_enc_W = (const float*)d_in[4];
    const float* att_enc_b = (const float*)d_in[5];
    const float* att_dec_W = (const float*)d_in[6];
    const float* att_dec_b = (const float*)d_in[7];
    const float* att_full_w = (const float*)d_in[8];
    const float* att_full_b = (const float*)d_in[9];
    const float* lstm_Wih = (const float*)d_in[10];
    const float* lstm_Whh = (const float*)d_in[11];
    const float* lstm_bih = (const float*)d_in[12];
    const float* lstm_bhh = (const float*)d_in[13];
    const float* initH_W  = (const float*)d_in[14];
    const float* initH_b  = (const float*)d_in[15];
    const float* initC_W  = (const float*)d_in[16];
    const float* initC_b  = (const float*)d_in[17];
    const float* fbeta_W  = (const float*)d_in[18];
    const float* fbeta_b  = (const float*)d_in[19];
    const float* fc_W     = (const float*)d_in[20];
    const float* fc_b     = (const float*)d_in[21];

    // outputs (flat f32): preds | caps | dec_len | alphas | order
    float* o = (float*)d_out;
    float* preds_out  = o;
    float* caps_out   = o + (size_t)BATCH * TSTEPS * VOC;
    float* declen_out = caps_out + (size_t)BATCH * LCAP;
    float* order_out  = declen_out + BATCH;
    float* alphas_out = order_out + BATCH;

    // workspace layout
    char* wsb = (char*)d_ws;
    int* i_order  = (int*)wsb;
    int* i_declen = i_order + 64;
    float* f = (float*)(wsb + 512);
    float* f_mean  = f;  f += (size_t)BATCH * ENCD;
    float* f_h     = f;  f += (size_t)BATCH * DECD;
    float* f_c     = f;  f += (size_t)BATCH * DECD;
    float* f_att2  = f;  f += (size_t)BATCH * ATTD;
    float* f_gate  = f;  f += (size_t)BATCH * ENCD;
    float* f_e     = f;  f += (size_t)BATCH * PIX;
    f = (float*)(((uintptr_t)f + 255) & ~(uintptr_t)255);
    float* f_part  = f;  f += (size_t)6 * BATCH * 2048;
    float* f_hall  = f;  f += (size_t)TSTEPS * BATCH * DECD;
    f = (float*)(((uintptr_t)f + 255) & ~(uintptr_t)255);
    unsigned short* bf = (unsigned short*)f;
    unsigned short* xh_bf   = bf;  bf += (size_t)BATCH * XHDIM;
    unsigned short* att1_bf = bf;  bf += (size_t)BATCH * PIX * ATTD;
    unsigned short* Wad_bf  = bf;  bf += (size_t)DECD * ATTD;
    unsigned short* Wfb_bf  = bf;  bf += (size_t)DECD * ENCD;
    unsigned short* Wcomb_bf = bf; bf += (size_t)2048 * XHDIM;
    unsigned short* Wfc_bf  = bf;  bf += (size_t)DECD * VOC;
    bf = (unsigned short*)(((uintptr_t)bf + 255) & ~(uintptr_t)255);
    unsigned short* enc_bf  = bf;  bf += (size_t)BATCH * PIX * ENCD;

    // ---- one-time setup ----
    k_setup<<<1, 64, 0, stream>>>(caps, lens, i_order, i_declen,
                                  caps_out, declen_out, order_out);
    k_cvt<<<(DECD * ATTD) / 1024, 256, 0, stream>>>(att_dec_W, Wad_bf, DECD * ATTD);
    k_cvt<<<(DECD * ENCD) / 1024, 256, 0, stream>>>(fbeta_W, Wfb_bf, DECD * ENCD);
    k_cvt<<<(DECD * VOC) / 1024 + 1, 256, 0, stream>>>(fc_W, Wfc_bf, DECD * VOC);
    k_cvt_comb<<<2048, 256, 0, stream>>>(lstm_Wih, lstm_Whh, Wcomb_bf);
    k_cvt_enc<<<dim3(BATCH, PIX), 256, 0, stream>>>(enc, i_order, enc_bf);
    k_mean<<<dim3(BATCH, ENCD / 256), 256, 0, stream>>>(enc, i_order, f_mean);
    k_h0c0<<<16, 256, 0, stream>>>(f_mean, initH_W, initH_b, initC_W, initC_b,
                                   f_h, f_c, xh_bf);
    k_att1<<<dim3(196, 8), 256, 0, stream>>>(enc, i_order, att_enc_W, att_enc_b,
                                             att1_bf);

    // ---- recurrence ----
    for (int t = 0; t < TSTEPS; ++t) {
        k_att2gate<<<dim3(10, 8), 256, 0, stream>>>(f_h, Wad_bf, att_dec_b,
                                                    Wfb_bf, fbeta_b, embW, caps,
                                                    i_order, f_att2, f_gate, xh_bf, t);
        k_e<<<dim3(BATCH, 49), 256, 0, stream>>>(att1_bf, f_att2, att_full_w,
                                                 att_full_b, f_e);
        k_awe<<<dim3(BATCH, 8), 256, 0, stream>>>(f_e, enc_bf, f_gate, i_declen,
                                                  xh_bf, alphas_out, t);
        k_gates<<<dim3(32, 6), 256, 0, stream>>>(xh_bf, Wcomb_bf, f_part);
        k_update<<<BATCH, DECD, 0, stream>>>(f_part, lstm_bih, lstm_bhh, i_declen,
                                             f_h, f_c, f_hall, xh_bf, t);
    }

    k_fc<<<dim3((VOC + 63) / 64, TSTEPS), 256, 0, stream>>>(f_hall, Wfc_bf, fc_b,
                                                            i_declen, preds_out);
}